// Round 7
// baseline (453.291 us; speedup 1.0000x reference)
//
#include <hip/hip_runtime.h>
#include <math.h>

// ---------------------------------------------------------------------------
// InfoNCE on MI355X — v10.
// T1[i,j] = tail(relu(hx[j]+hy[i]+b1)) = fused GEMM M=262144, N=512, K=512,
// A formed on the fly; 2 MFMA products (A bf16, B hi/lo split), 32x32x16.
// v10 vs v9: K-ROTATED WAVE STAGGER. v5/v6/v8/v9 (four different structures)
// all pinned at 41-43% MfmaUtil with every per-CU resource individually
// under budget -> the shared defect is post-barrier lockstep: all waves hit
// ds_read bursts / waitcnts / MFMA clusters simultaneously, so LDS port,
// L2 and the matrix pipe are used in alternating bursts, never overlapped.
// Fix: accumulation over k commutes, so wave w runs the K-loop starting at
// half-step kk0=2w (mod 32) and wraps -> 16 waves permanently offset by 2
// half-steps, zero extra registers, no barriers. Geometry = v6 (M-tile 128,
// 1024 thr, 16 waves, wave tile 128x32, acc 64 AGPR + ~64 arch = 128 cap,
// 4 waves/SIMD; B traffic 2.1 GB = ~32 B/cyc/CU, well under L2 ~56).
// Also: row-LSE fused into pair epilogue (atomicAdd of per-block exp-sums,
// T1 never materialized; rowlse kernel removed).
// ---------------------------------------------------------------------------

typedef __bf16 bf16x8 __attribute__((ext_vector_type(8)));
typedef float  f32x16 __attribute__((ext_vector_type(16)));

#define H    512
#define NPTS 512
#define XD   128
#define SPA  520   // A-tile LDS row stride (elems): 1040 B (0 conflicts, v6)
#define PLS  132   // epilogue partial-scratch row stride (f32)

// ---------------- prep: hx, hy(+b1); W2 -> fragment-major bf16 hi/lo ------
__global__ __launch_bounds__(256) void prep_kernel(
    const float* __restrict__ x, const float* __restrict__ y,
    const float* __restrict__ W1x, const float* __restrict__ W1y,
    const float* __restrict__ b1, const float* __restrict__ W2,
    float* __restrict__ hx, float* __restrict__ hy,
    __bf16* __restrict__ w2h, __bf16* __restrict__ w2l) {
  __shared__ float xr[XD];
  const int b = blockIdx.x;
  const int t = threadIdx.x;
  if (b < 2 * NPTS) {
    const bool isY = (b >= NPTS);
    const int row = isY ? b - NPTS : b;
    const float* src = isY ? y : x;      // [NPTS][XD]
    const float* W   = isY ? W1y : W1x;  // [XD][H]
    if (t < XD) xr[t] = src[row * XD + t];
    __syncthreads();
    for (int c = t; c < H; c += 256) {
      float s = 0.f;
#pragma unroll
      for (int k = 0; k < XD; ++k) s = fmaf(xr[k], W[k * H + c], s);
      if (isY) hy[row * H + c] = s + b1[c];   // fold b1 into hy
      else     hx[row * H + c] = s;
    }
  } else {
    // W2[k][n] -> 32x32x16-fragment-major:
    // idx = ((n>>5)*32 + (k>>4))*512 + (n&31)*16 + (k&15)
    // one 1KB frag = 32 cols x 16 k; lane l holds col = l&31, k = (l>>5)*8+e.
    const int n = b - 2 * NPTS;
    for (int k = t; k < H; k += 256) {
      float v = W2[k * H + n];
      __bf16 hi = (__bf16)v;
      float lo = v - (float)hi;
      const int idx = (((n >> 5) * 32) + (k >> 4)) * 512 + (n & 31) * 16 + (k & 15);
      w2h[idx] = hi;
      w2l[idx] = (__bf16)lo;
    }
  }
}

// ---------------- pair GEMM + fused tail + row exp-sums -------------------
// grid 2048 = 32 i-groups x 64 j-groups; M-tile = 128 pairs (16 i x 8 j).
// 1024 threads = 16 waves; wave w: all 128 rows x cols [w*32, w*32+32)
// (4 m-tiles, 1 n-group; acc[4] f32x16 = 64 AGPR). K in 32 half-steps of
// 16, wave w visits them in order kk0+it mod 32 with kk0 = 2w (stagger).
// Barrier-free K-loop; full-K A tile in 133 KB dynamic LDS.
__global__ __launch_bounds__(1024, 4) void pair_kernel(
    const float* __restrict__ hx, const float* __restrict__ hy,
    const __bf16* __restrict__ w2h, const __bf16* __restrict__ w2l,
    const float* __restrict__ b2, const float* __restrict__ W3,
    const float* __restrict__ b3, float* __restrict__ t0g,
    float* __restrict__ rowsum) {
  extern __shared__ __align__(16) __bf16 Ah[];   // [128][SPA] = 133120 B

  const int t    = threadIdx.x;
  const int i0   = (blockIdx.x >> 6) * 16;
  const int j0   = (blockIdx.x & 63) * 8;
  const int wave = t >> 6;        // n-group 0..15 (cols wave*32..wave*32+31)
  const int lane = t & 63;
  const int r31  = lane & 31;
  const int half = lane >> 5;

  // B frag addressing: group g = wave; frag(kk) at g*16384 + kk*512 + boff
  const int boff = r31 * 16 + half * 8;
  const __bf16* w2hW = w2h + wave * 16384 + boff;
  const __bf16* w2lW = w2l + wave * 16384 + boff;

  const int kk0 = (wave * 2) & 31;   // per-wave K-schedule rotation

  // issue B loads for this wave's FIRST half-step before staging
  bf16x8 Bh[2], Bl[2];
  Bh[0] = *(const bf16x8*)(w2hW + kk0 * 512);
  Bl[0] = *(const bf16x8*)(w2lW + kk0 * 512);

  // ---- upfront staging of the whole 128 x 512 A tile (v6 pattern) ----
  // 8 threads per row, 8 segs (of 8 elems) per thread.
  {
    const int sm = t >> 3;        // pair row 0..127  (ti = sm>>3, tj = sm&7)
    const int sl = t & 7;
    const float* hxp = hx + (j0 + (sm & 7)) * H;
    const float* hyp = hy + (i0 + (sm >> 3)) * H;
    __bf16* arow = Ah + sm * SPA;
#pragma unroll
    for (int c = 0; c < 8; ++c) {
      const int k = sl * 8 + c * 64;
      float4 x0 = *(const float4*)(hxp + k);
      float4 x1 = *(const float4*)(hxp + k + 4);
      float4 y0 = *(const float4*)(hyp + k);
      float4 y1 = *(const float4*)(hyp + k + 4);
      float a[8] = {x0.x + y0.x, x0.y + y0.y, x0.z + y0.z, x0.w + y0.w,
                    x1.x + y1.x, x1.y + y1.y, x1.z + y1.z, x1.w + y1.w};
      bf16x8 hv;
#pragma unroll
      for (int e = 0; e < 8; ++e) {
        float v = a[e] > 0.f ? a[e] : 0.f;   // first relu
        hv[e] = (__bf16)v;
      }
      *(bf16x8*)(&arow[k]) = hv;
    }
  }

  // A-frag LDS base offsets (elems): row = mt*32 + r31, +kk*16 + half*8
  int aoff[4];
#pragma unroll
  for (int mt = 0; mt < 4; ++mt) aoff[mt] = (mt * 32 + r31) * SPA + half * 8;

  f32x16 acc[4] = {};

  __syncthreads();   // staging complete; only barrier before epilogue

  // ---- barrier-free, K-rotated loop: 32 half-steps of K=16 -----------
  int kk = kk0;
#pragma unroll 2
  for (int it = 0; it < 32; ++it) {
    const int cur = it & 1;
    const int ko = kk * 16;
    bf16x8 a0 = *(const bf16x8*)(Ah + aoff[0] + ko);
    bf16x8 a1 = *(const bf16x8*)(Ah + aoff[1] + ko);
    bf16x8 a2 = *(const bf16x8*)(Ah + aoff[2] + ko);
    bf16x8 a3 = *(const bf16x8*)(Ah + aoff[3] + ko);
    if (it < 31) {   // prefetch B for next half-step (wrapped)
      const int kn = ((kk + 1) & 31) << 9;
      Bh[cur ^ 1] = *(const bf16x8*)(w2hW + kn);
      Bl[cur ^ 1] = *(const bf16x8*)(w2lW + kn);
    }
    // 8 MFMA: 4 independent Bh products, then 4 Bl (dep distance 4)
    __builtin_amdgcn_s_setprio(1);
    acc[0] = __builtin_amdgcn_mfma_f32_32x32x16_bf16(a0, Bh[cur], acc[0], 0, 0, 0);
    acc[1] = __builtin_amdgcn_mfma_f32_32x32x16_bf16(a1, Bh[cur], acc[1], 0, 0, 0);
    acc[2] = __builtin_amdgcn_mfma_f32_32x32x16_bf16(a2, Bh[cur], acc[2], 0, 0, 0);
    acc[3] = __builtin_amdgcn_mfma_f32_32x32x16_bf16(a3, Bh[cur], acc[3], 0, 0, 0);
    acc[0] = __builtin_amdgcn_mfma_f32_32x32x16_bf16(a0, Bl[cur], acc[0], 0, 0, 0);
    acc[1] = __builtin_amdgcn_mfma_f32_32x32x16_bf16(a1, Bl[cur], acc[1], 0, 0, 0);
    acc[2] = __builtin_amdgcn_mfma_f32_32x32x16_bf16(a2, Bl[cur], acc[2], 0, 0, 0);
    acc[3] = __builtin_amdgcn_mfma_f32_32x32x16_bf16(a3, Bl[cur], acc[3], 0, 0, 0);
    __builtin_amdgcn_s_setprio(0);
    kk = (kk + 1) & 31;
  }

  __syncthreads();   // all waves done reading Ah -> safe to alias its LDS

  // epilogue: v = relu(h2 + b2); p = v*W3; 2-stage shfl (4 cols) ->
  // partials PL[row][128] in LDS (aliasing dead A tile); final 128-thread
  // reduce + softplus; diag -> t0g, row exp-sums -> atomicAdd(rowsum).
  float* PL = (float*)Ah;            // [128][PLS]
  const float bb  = b2[wave * 32 + r31];
  const float w3v = W3[wave * 32 + r31];
  const int cg = wave * 8 + (r31 >> 2);   // partial-col 0..127
#pragma unroll
  for (int mt = 0; mt < 4; ++mt) {
#pragma unroll
    for (int r = 0; r < 16; ++r) {
      float v = acc[mt][r] + bb;
      v = v > 0.f ? v : 0.f;               // second relu
      float p = v * w3v;
      p += __shfl_xor(p, 1);
      p += __shfl_xor(p, 2);
      if ((r31 & 3) == 0) {
        const int row = mt * 32 + (r & 3) + 8 * (r >> 2) + 4 * half;
        PL[row * PLS + cg] = p;
      }
    }
  }
  __syncthreads();
  if (t < 128) {
    float s = b3[0];
    const float* pr = PL + t * PLS;
#pragma unroll
    for (int c = 0; c < 32; ++c) {
      float4 q = *(const float4*)(pr + c * 4);
      s += q.x + q.y + q.z + q.w;
    }
    const float sp = s > 0.f ? s + log1pf(expf(-s)) : log1pf(expf(s));
    const int ti = t >> 3, tj = t & 7;
    const int gi = i0 + ti, gj = j0 + tj;
    if (gi == gj) t0g[gi] = sp;            // diag == T0 (written exactly once)
    float e = expf(sp);
    e += __shfl_xor(e, 1);                 // sum over this block's 8 j's
    e += __shfl_xor(e, 2);
    e += __shfl_xor(e, 4);
    if (tj == 0) atomicAdd(rowsum + gi, e);
  }
}

// ---------------- final: mean(T0) - (mean(log rowsum) - log N) ------------
__global__ __launch_bounds__(512) void final_kernel(
    const float* __restrict__ t0g, const float* __restrict__ rowsum,
    float* __restrict__ out) {
  __shared__ float s1[8], s2[8];
  const int t = threadIdx.x, lane = t & 63, w = t >> 6;
  float a = t0g[t];
  float b = logf(rowsum[t]);
#pragma unroll
  for (int off = 1; off < 64; off <<= 1) {
    a += __shfl_xor(a, off);
    b += __shfl_xor(b, off);
  }
  if (lane == 0) { s1[w] = a; s2[w] = b; }
  __syncthreads();
  if (t == 0) {
    float sa = 0.f, sb = 0.f;
#pragma unroll
    for (int i = 0; i < 8; ++i) { sa += s1[i]; sb += s2[i]; }
    out[0] = sa / 512.0f - sb / 512.0f + logf(512.0f);
  }
}

// ---------------------------------------------------------------------------
extern "C" void kernel_launch(void* const* d_in, const int* in_sizes, int n_in,
                              void* d_out, int out_size, void* d_ws, size_t ws_size,
                              hipStream_t stream) {
  const float* x   = (const float*)d_in[0];
  const float* y   = (const float*)d_in[1];
  const float* W1x = (const float*)d_in[2];
  const float* W1y = (const float*)d_in[3];
  const float* b1  = (const float*)d_in[4];
  const float* W2  = (const float*)d_in[5];
  const float* b2  = (const float*)d_in[6];
  const float* W3  = (const float*)d_in[7];
  const float* b3  = (const float*)d_in[8];

  float* ws = (float*)d_ws;
  float* hx  = ws;                        // 512*512 f32
  float* hy  = ws + 262144;               // 512*512 f32
  float* t0g = ws + 524288;               // 512 f32 (diag = T0)
  float* rsm = ws + 524288 + 512;         // 512 f32 (row exp-sums)
  __bf16* w2h = (__bf16*)(ws + 786432);   // 512*512 bf16 (fragment-major)
  __bf16* w2l = w2h + 262144;             // 512*512 bf16
  float* out = (float*)d_out;

  // dynamic LDS: 128 rows x SPA(520) x 2B = 133120 B (>64 KB default cap)
  static bool configured = false;
  if (!configured) {
    hipFuncSetAttribute(reinterpret_cast<const void*>(pair_kernel),
                        hipFuncAttributeMaxDynamicSharedMemorySize,
                        128 * SPA * 2);
    configured = true;
  }

  hipMemsetAsync(rsm, 0, 512 * sizeof(float), stream);
  hipLaunchKernelGGL(prep_kernel, dim3(1536), dim3(256), 0, stream,
                     x, y, W1x, W1y, b1, W2, hx, hy, w2h, w2l);
  hipLaunchKernelGGL(pair_kernel, dim3(2048), dim3(1024), 128 * SPA * 2, stream,
                     hx, hy, w2h, w2l, b2, W3, b3, t0g, rsm);
  hipLaunchKernelGGL(final_kernel, dim3(1), dim3(512), 0, stream, t0g, rsm, out);
}